// Round 1
// baseline (647.416 us; speedup 1.0000x reference)
//
#include <hip/hip_runtime.h>

#define SEQL 2048
#define DMODEL 1024
#define HDIM 8192  // H*D

typedef unsigned short bf16_t;
typedef __attribute__((ext_vector_type(8))) short bf16x8;
typedef __attribute__((ext_vector_type(4))) float f32x4;

__device__ __forceinline__ bf16_t f2bf(float f) {
  unsigned u = __float_as_uint(f);
  u += 0x7fffu + ((u >> 16) & 1u);  // RNE
  return (bf16_t)(u >> 16);
}
__device__ __forceinline__ float bf2f(bf16_t b) {
  return __uint_as_float(((unsigned)b) << 16);
}
__device__ __forceinline__ void st(bf16_t* p, float v) { *p = f2bf(v); }
__device__ __forceinline__ void st(float* p, float v) { *p = v; }

// ---------------- elementwise f32 -> bf16 ----------------
__global__ __launch_bounds__(256) void cvt_f32_bf16(const float* __restrict__ in,
                                                    bf16_t* __restrict__ out, int n) {
  int i = (blockIdx.x * 256 + threadIdx.x) * 4;
  if (i >= n) return;
  float4 f = *reinterpret_cast<const float4*>(in + i);
  ushort4 u;
  u.x = f2bf(f.x); u.y = f2bf(f.y); u.z = f2bf(f.z); u.w = f2bf(f.w);
  *reinterpret_cast<ushort4*>(out + i) = u;
}

// tokens (DMODEL x SEQL) f32 -> tokensT (SEQL x DMODEL) bf16
__global__ __launch_bounds__(256) void transpose_cvt(const float* __restrict__ in,
                                                     bf16_t* __restrict__ out) {
  __shared__ float tile[32][33];
  int bx = blockIdx.x * 32;  // seq j
  int by = blockIdx.y * 32;  // channel c
  int tx = threadIdx.x, ty = threadIdx.y;
#pragma unroll
  for (int i = ty; i < 32; i += 8)
    tile[i][tx] = in[(size_t)(by + i) * SEQL + bx + tx];
  __syncthreads();
#pragma unroll
  for (int i = ty; i < 32; i += 8)
    out[(size_t)(bx + i) * DMODEL + by + tx] = f2bf(tile[tx][i]);
}

// Vsplit[h][d][m] = Vm[4m+h2, r*1024+d]  (h = 2*h2 + r), bf16 -> bf16
__global__ __launch_bounds__(256) void vsplit_k(const bf16_t* __restrict__ Vm,
                                                bf16_t* __restrict__ Vs) {
  __shared__ bf16_t tile[32][33];
  int h = blockIdx.z, h2 = h >> 1, r = h & 1;
  int m0 = blockIdx.x * 32, d0 = blockIdx.y * 32;
  int tx = threadIdx.x, ty = threadIdx.y;
#pragma unroll
  for (int i = ty; i < 32; i += 8)  // i: m offset, tx: d offset
    tile[i][tx] = Vm[(size_t)(4 * (m0 + i) + h2) * SEQL + r * DMODEL + d0 + tx];
  __syncthreads();
#pragma unroll
  for (int i = ty; i < 32; i += 8)  // i: d offset, tx: m offset
    Vs[((size_t)h * DMODEL + d0 + i) * SEQL + m0 + tx] = tile[tx][i];
}

// softmax over the 8 heads (dim 0), in place on bf16 S[8][L*L]
__global__ __launch_bounds__(256) void softmax_heads(bf16_t* __restrict__ S) {
  const size_t HS = (size_t)SEQL * SEQL;
  size_t p = ((size_t)blockIdx.x * 256 + threadIdx.x) * 8;
  float v[8][8];
#pragma unroll
  for (int h = 0; h < 8; ++h) {
    bf16x8 x = *reinterpret_cast<const bf16x8*>(S + h * HS + p);
#pragma unroll
    for (int e = 0; e < 8; ++e) v[h][e] = bf2f((bf16_t)x[e]);
  }
#pragma unroll
  for (int e = 0; e < 8; ++e) {
    float mx = v[0][e];
#pragma unroll
    for (int h = 1; h < 8; ++h) mx = fmaxf(mx, v[h][e]);
    float s = 0.f;
#pragma unroll
    for (int h = 0; h < 8; ++h) { v[h][e] = __expf(v[h][e] - mx); s += v[h][e]; }
    float inv = 1.0f / s;
#pragma unroll
    for (int h = 0; h < 8; ++h) v[h][e] *= inv;
  }
#pragma unroll
  for (int h = 0; h < 8; ++h) {
    bf16x8 x;
#pragma unroll
    for (int e = 0; e < 8; ++e) x[e] = (short)f2bf(v[h][e]);
    *reinterpret_cast<bf16x8*>(S + h * HS + p) = x;
  }
}

// ---------------- C = scale * A·B^T (+bias[row]) ----------------
// A: M x K (row stride lda), B: N x K (row stride ldb), both bf16 K-contiguous.
// 128x128 tile, 4 waves (2x2 of 64x64), BK=32, mfma_f32_16x16x32_bf16.
// blockIdx.z batching via element strides sA/sB/sC.
template <typename OutT, bool HAS_BIAS>
__global__ __launch_bounds__(256) void gemm_bt(
    const bf16_t* __restrict__ A, const bf16_t* __restrict__ B,
    OutT* __restrict__ C, const float* __restrict__ bias,
    int M, int N, int K, int lda, int ldb, int ldc,
    long long sA, long long sB, long long sC, float scale) {
  __shared__ alignas(16) bf16_t As[128 * 32];
  __shared__ alignas(16) bf16_t Bs[128 * 32];
  const int z = blockIdx.z;
  A += (long long)z * sA;
  B += (long long)z * sB;
  C += (long long)z * sC;
  const int brow = blockIdx.y * 128;
  const int bcol = blockIdx.x * 128;
  const int t = threadIdx.x;
  const int w = t >> 6, lane = t & 63;
  const int fr = lane & 15, fq = lane >> 4;
  const int wr = w >> 1, wc = w & 1;

  f32x4 acc[4][4];
  const f32x4 fzero = {0.f, 0.f, 0.f, 0.f};
#pragma unroll
  for (int m = 0; m < 4; ++m)
#pragma unroll
    for (int n = 0; n < 4; ++n) acc[m][n] = fzero;

  for (int kk = 0; kk < K; kk += 32) {
    // stage 128x32 bf16 tiles of A and B: per wave-chunk ci, lane l writes
    // LDS bytes ci*1024 + l*16 (HW: wave-uniform base + lane*16).
#pragma unroll
    for (int i = 0; i < 2; ++i) {
      const int ci = w + i * 4;            // wave-uniform chunk id 0..7
      const int idx = ci * 64 + lane;      // 0..511 (16B units)
      const int row = idx >> 2;            // 0..127
      const int c8 = (idx & 3) << 3;       // 0,8,16,24
      const bf16_t* ga = A + (size_t)(brow + row) * lda + kk + c8;
      const bf16_t* gb = B + (size_t)(bcol + row) * ldb + kk + c8;
      __builtin_amdgcn_global_load_lds(
          (const __attribute__((address_space(1))) void*)ga,
          (__attribute__((address_space(3))) void*)(As + ci * 512), 16, 0, 0);
      __builtin_amdgcn_global_load_lds(
          (const __attribute__((address_space(1))) void*)gb,
          (__attribute__((address_space(3))) void*)(Bs + ci * 512), 16, 0, 0);
    }
    __syncthreads();
    bf16x8 af[4], bg[4];
#pragma unroll
    for (int m = 0; m < 4; ++m)
      af[m] = *reinterpret_cast<const bf16x8*>(As + (wr * 64 + m * 16 + fr) * 32 + fq * 8);
#pragma unroll
    for (int n = 0; n < 4; ++n)
      bg[n] = *reinterpret_cast<const bf16x8*>(Bs + (wc * 64 + n * 16 + fr) * 32 + fq * 8);
#pragma unroll
    for (int m = 0; m < 4; ++m)
#pragma unroll
      for (int n = 0; n < 4; ++n)
        acc[m][n] = __builtin_amdgcn_mfma_f32_16x16x32_bf16(af[m], bg[n], acc[m][n], 0, 0, 0);
    __syncthreads();
  }

  // epilogue: C/D layout col = lane&15, row = (lane>>4)*4 + j  (m89/m91)
#pragma unroll
  for (int m = 0; m < 4; ++m) {
#pragma unroll
    for (int j = 0; j < 4; ++j) {
      const int orow = brow + wr * 64 + m * 16 + fq * 4 + j;
      float bvv = 0.f;
      if (HAS_BIAS) bvv = bias[orow];
#pragma unroll
      for (int n = 0; n < 4; ++n) {
        const int ocol = bcol + wc * 64 + n * 16 + fr;
        st(&C[(size_t)orow * ldc + ocol], acc[m][n][j] * scale + bvv);
      }
    }
  }
}

extern "C" void kernel_launch(void* const* d_in, const int* in_sizes, int n_in,
                              void* d_out, int out_size, void* d_ws, size_t ws_size,
                              hipStream_t stream) {
  const float* tokens = (const float*)d_in[0];
  const float* Wq = (const float*)d_in[1];
  const float* bq = (const float*)d_in[2];
  const float* Wk = (const float*)d_in[3];
  const float* bk = (const float*)d_in[4];
  const float* Wv = (const float*)d_in[5];
  const float* bv = (const float*)d_in[6];
  const float* Wo = (const float*)d_in[7];
  const float* bo = (const float*)d_in[8];
  float* out = (float*)d_out;
  char* ws = (char*)d_ws;
  const size_t MB = 1024ull * 1024ull;
  // workspace layout (peak 180 MB with slot reuse)
  bf16_t* tT = (bf16_t*)(ws + 0);         // tokensT  4 MB   [0,4)
  bf16_t* Wb = (bf16_t*)(ws + 4 * MB);    // weight slot 16 MB [4,20)
  bf16_t* Qm = (bf16_t*)(ws + 20 * MB);   // 32 MB [20,52)
  bf16_t* Km = (bf16_t*)(ws + 52 * MB);   // 32 MB [52,84)
  bf16_t* Vm = (bf16_t*)(ws + 84 * MB);   // 32 MB [84,116)
  bf16_t* Sb = (bf16_t*)(ws + 116 * MB);  // scores/attn 64 MB [116,180)
  bf16_t* Vs = (bf16_t*)(ws + 20 * MB);   // Vsplit 32 MB (reuse Qm after scores)
  bf16_t* cT = (bf16_t*)(ws + 52 * MB);   // ctxT  32 MB (reuse Km after scores)

  dim3 b256(256);
  const int nW = HDIM * DMODEL;  // 8388608

  // tokens -> tokensT (bf16)
  transpose_cvt<<<dim3(SEQL / 32, DMODEL / 32), dim3(32, 8), 0, stream>>>(tokens, tT);

  // Q projection: Qm = Wq · tokensT^T + bq
  cvt_f32_bf16<<<nW / 1024, b256, 0, stream>>>(Wq, Wb, nW);
  gemm_bt<bf16_t, true><<<dim3(16, 64, 1), b256, 0, stream>>>(
      Wb, tT, Qm, bq, HDIM, SEQL, DMODEL, DMODEL, DMODEL, SEQL, 0, 0, 0, 1.0f);
  // K projection
  cvt_f32_bf16<<<nW / 1024, b256, 0, stream>>>(Wk, Wb, nW);
  gemm_bt<bf16_t, true><<<dim3(16, 64, 1), b256, 0, stream>>>(
      Wb, tT, Km, bk, HDIM, SEQL, DMODEL, DMODEL, DMODEL, SEQL, 0, 0, 0, 1.0f);
  // V projection
  cvt_f32_bf16<<<nW / 1024, b256, 0, stream>>>(Wv, Wb, nW);
  gemm_bt<bf16_t, true><<<dim3(16, 64, 1), b256, 0, stream>>>(
      Wb, tT, Vm, bv, HDIM, SEQL, DMODEL, DMODEL, DMODEL, SEQL, 0, 0, 0, 1.0f);

  // scores[h][l,m] = (1/32) dot(Qm[l*8192 + h*1024 + :], Km[m*8192 + h*1024 + :])
  gemm_bt<bf16_t, false><<<dim3(16, 16, 8), b256, 0, stream>>>(
      Qm, Km, Sb, nullptr, SEQL, SEQL, DMODEL, HDIM, HDIM, SEQL,
      1024, 1024, (long long)SEQL * SEQL, 0.03125f);

  // softmax over heads (dim 0), in place
  softmax_heads<<<(SEQL * SEQL / 8) / 256, b256, 0, stream>>>(Sb);

  // Vsplit gather
  vsplit_k<<<dim3(SEQL / 32, DMODEL / 32, 8), dim3(32, 8), 0, stream>>>(Vm, Vs);

  // ctxT[l, h*1024+d] = sum_m attn[h][l,m] * Vsplit[h][d,m]
  gemm_bt<bf16_t, false><<<dim3(8, 16, 8), b256, 0, stream>>>(
      Sb, Vs, cT, nullptr, SEQL, DMODEL, SEQL, SEQL, SEQL, HDIM,
      (long long)SEQL * SEQL, (long long)DMODEL * SEQL, DMODEL, 1.0f);

  // out = Wo · ctxT^T + bo  (f32 output)
  cvt_f32_bf16<<<nW / 1024, b256, 0, stream>>>(Wo, Wb, nW);
  gemm_bt<float, true><<<dim3(16, 8, 1), b256, 0, stream>>>(
      Wb, cT, out, bo, DMODEL, SEQL, HDIM, HDIM, HDIM, SEQL, 0, 0, 0, 1.0f);
}

// Round 2
// 551.335 us; speedup vs baseline: 1.1743x; 1.1743x over previous
//
#include <hip/hip_runtime.h>

#define SEQL 2048
#define DMODEL 1024
#define HDIM 8192  // H*D

typedef unsigned short bf16_t;
typedef __attribute__((ext_vector_type(8))) short bf16x8;
typedef __attribute__((ext_vector_type(4))) float f32x4;

__device__ __forceinline__ bf16_t f2bf(float f) {
  unsigned u = __float_as_uint(f);
  u += 0x7fffu + ((u >> 16) & 1u);  // RNE
  return (bf16_t)(u >> 16);
}
__device__ __forceinline__ float bf2f(bf16_t b) {
  return __uint_as_float(((unsigned)b) << 16);
}
__device__ __forceinline__ void st(bf16_t* p, float v) { *p = f2bf(v); }
__device__ __forceinline__ void st(float* p, float v) { *p = v; }

// ---------------- elementwise f32 -> bf16 ----------------
__global__ __launch_bounds__(256) void cvt_f32_bf16(const float* __restrict__ in,
                                                    bf16_t* __restrict__ out, int n) {
  int i = (blockIdx.x * 256 + threadIdx.x) * 4;
  if (i >= n) return;
  float4 f = *reinterpret_cast<const float4*>(in + i);
  ushort4 u;
  u.x = f2bf(f.x); u.y = f2bf(f.y); u.z = f2bf(f.z); u.w = f2bf(f.w);
  *reinterpret_cast<ushort4*>(out + i) = u;
}

// tokens (DMODEL x SEQL) f32 -> tokensT (SEQL x DMODEL) bf16
__global__ __launch_bounds__(256) void transpose_cvt(const float* __restrict__ in,
                                                     bf16_t* __restrict__ out) {
  __shared__ float tile[32][33];
  int bx = blockIdx.x * 32;  // seq j
  int by = blockIdx.y * 32;  // channel c
  int tx = threadIdx.x, ty = threadIdx.y;
#pragma unroll
  for (int i = ty; i < 32; i += 8)
    tile[i][tx] = in[(size_t)(by + i) * SEQL + bx + tx];
  __syncthreads();
#pragma unroll
  for (int i = ty; i < 32; i += 8)
    out[(size_t)(bx + i) * DMODEL + by + tx] = f2bf(tile[tx][i]);
}

// Vsplit[h][d][m] = Vm[4m+h2, r*1024+d]  (h = 2*h2 + r), bf16 -> bf16
__global__ __launch_bounds__(256) void vsplit_k(const bf16_t* __restrict__ Vm,
                                                bf16_t* __restrict__ Vs) {
  __shared__ bf16_t tile[32][33];
  int h = blockIdx.z, h2 = h >> 1, r = h & 1;
  int m0 = blockIdx.x * 32, d0 = blockIdx.y * 32;
  int tx = threadIdx.x, ty = threadIdx.y;
#pragma unroll
  for (int i = ty; i < 32; i += 8)  // i: m offset, tx: d offset
    tile[i][tx] = Vm[(size_t)(4 * (m0 + i) + h2) * SEQL + r * DMODEL + d0 + tx];
  __syncthreads();
#pragma unroll
  for (int i = ty; i < 32; i += 8)  // i: d offset, tx: m offset
    Vs[((size_t)h * DMODEL + d0 + i) * SEQL + m0 + tx] = tile[tx][i];
}

// softmax over the 8 heads (dim 0), in place on bf16 S[8][L*L]
__global__ __launch_bounds__(256) void softmax_heads(bf16_t* __restrict__ S) {
  const size_t HS = (size_t)SEQL * SEQL;
  size_t p = ((size_t)blockIdx.x * 256 + threadIdx.x) * 8;
  float v[8][8];
#pragma unroll
  for (int h = 0; h < 8; ++h) {
    bf16x8 x = *reinterpret_cast<const bf16x8*>(S + h * HS + p);
#pragma unroll
    for (int e = 0; e < 8; ++e) v[h][e] = bf2f((bf16_t)x[e]);
  }
#pragma unroll
  for (int e = 0; e < 8; ++e) {
    float mx = v[0][e];
#pragma unroll
    for (int h = 1; h < 8; ++h) mx = fmaxf(mx, v[h][e]);
    float s = 0.f;
#pragma unroll
    for (int h = 0; h < 8; ++h) { v[h][e] = __expf(v[h][e] - mx); s += v[h][e]; }
    float inv = 1.0f / s;
#pragma unroll
    for (int h = 0; h < 8; ++h) v[h][e] *= inv;
  }
#pragma unroll
  for (int h = 0; h < 8; ++h) {
    bf16x8 x;
#pragma unroll
    for (int e = 0; e < 8; ++e) x[e] = (short)f2bf(v[h][e]);
    *reinterpret_cast<bf16x8*>(S + h * HS + p) = x;
  }
}

// reduce 8 f32 split-K partials P[z][D][L] -> out[D][L] + bias[row]
__global__ __launch_bounds__(256) void reduce_out(const float* __restrict__ P,
                                                  const float* __restrict__ bo,
                                                  float* __restrict__ out) {
  const size_t NEL = (size_t)DMODEL * SEQL;
  size_t i = ((size_t)blockIdx.x * 256 + threadIdx.x) * 4;
  float4 a = *reinterpret_cast<const float4*>(P + i);
#pragma unroll
  for (int z = 1; z < 8; ++z) {
    float4 b = *reinterpret_cast<const float4*>(P + z * NEL + i);
    a.x += b.x; a.y += b.y; a.z += b.z; a.w += b.w;
  }
  float bias = bo[i / SEQL];
  a.x += bias; a.y += bias; a.z += bias; a.w += bias;
  *reinterpret_cast<float4*>(out + i) = a;
}

// ---------------- C = scale * A·B^T (+bias[row]) ----------------
// A: M x K (row stride lda), B: N x K (row stride ldb), both bf16 K-contiguous.
// 128x128 tile, 4 waves (2x2 of 64x64), BK=32, mfma_f32_16x16x32_bf16.
// blockIdx.z batching via element strides sA/sB/sC (also used for split-K:
// sA=sB=K-slice offset along the row, sC=partial-buffer stride).
// LDS tiles are XOR-swizzled BOTH SIDES (rule #21): the 16B chunk holding
// k-range [s*8, s*8+8) of row r lives at physical slot s ^ ((r>>1)&3); the
// global source is pre-swizzled to match the linear global_load_lds dest.
// This spreads a wave's 16 ds_read_b128 rows over all 8 slots of the 128B
// bank window -> 2-way (free) instead of 8-way.
template <typename OutT, bool HAS_BIAS>
__global__ __launch_bounds__(256) void gemm_bt(
    const bf16_t* __restrict__ A, const bf16_t* __restrict__ B,
    OutT* __restrict__ C, const float* __restrict__ bias,
    int M, int N, int K, int lda, int ldb, int ldc,
    long long sA, long long sB, long long sC, float scale) {
  __shared__ alignas(16) bf16_t As[128 * 32];
  __shared__ alignas(16) bf16_t Bs[128 * 32];
  const int z = blockIdx.z;
  A += (long long)z * sA;
  B += (long long)z * sB;
  C += (long long)z * sC;
  const int brow = blockIdx.y * 128;
  const int bcol = blockIdx.x * 128;
  const int t = threadIdx.x;
  const int w = t >> 6, lane = t & 63;
  const int fr = lane & 15, fq = lane >> 4;
  const int wr = w >> 1, wc = w & 1;

  f32x4 acc[4][4];
  const f32x4 fzero = {0.f, 0.f, 0.f, 0.f};
#pragma unroll
  for (int m = 0; m < 4; ++m)
#pragma unroll
    for (int n = 0; n < 4; ++n) acc[m][n] = fzero;

  for (int kk = 0; kk < K; kk += 32) {
    // stage 128x32 bf16 tiles of A and B: per wave-chunk ci, lane l writes
    // LDS bytes ci*1024 + l*16 (HW: wave-uniform base + lane*16).
#pragma unroll
    for (int i = 0; i < 2; ++i) {
      const int ci = w + i * 4;            // wave-uniform chunk id 0..7
      const int idx = ci * 64 + lane;      // 0..511 (16B units)
      const int row = idx >> 2;            // 0..127
      const int s = idx & 3;               // physical slot within row
      const int c8 = (s ^ ((row >> 1) & 3)) << 3;  // swizzled k-chunk
      const bf16_t* ga = A + (size_t)(brow + row) * lda + kk + c8;
      const bf16_t* gb = B + (size_t)(bcol + row) * ldb + kk + c8;
      __builtin_amdgcn_global_load_lds(
          (const __attribute__((address_space(1))) void*)ga,
          (__attribute__((address_space(3))) void*)(As + ci * 512), 16, 0, 0);
      __builtin_amdgcn_global_load_lds(
          (const __attribute__((address_space(1))) void*)gb,
          (__attribute__((address_space(3))) void*)(Bs + ci * 512), 16, 0, 0);
    }
    __syncthreads();
    bf16x8 af[4], bg[4];
#pragma unroll
    for (int m = 0; m < 4; ++m) {
      const int row = wr * 64 + m * 16 + fr;
      af[m] = *reinterpret_cast<const bf16x8*>(
          As + row * 32 + ((fq ^ ((row >> 1) & 3)) << 3));
    }
#pragma unroll
    for (int n = 0; n < 4; ++n) {
      const int row = wc * 64 + n * 16 + fr;
      bg[n] = *reinterpret_cast<const bf16x8*>(
          Bs + row * 32 + ((fq ^ ((row >> 1) & 3)) << 3));
    }
#pragma unroll
    for (int m = 0; m < 4; ++m)
#pragma unroll
      for (int n = 0; n < 4; ++n)
        acc[m][n] = __builtin_amdgcn_mfma_f32_16x16x32_bf16(af[m], bg[n], acc[m][n], 0, 0, 0);
    __syncthreads();
  }

  // epilogue: C/D layout col = lane&15, row = (lane>>4)*4 + j  (m89/m91)
#pragma unroll
  for (int m = 0; m < 4; ++m) {
#pragma unroll
    for (int j = 0; j < 4; ++j) {
      const int orow = brow + wr * 64 + m * 16 + fq * 4 + j;
      float bvv = 0.f;
      if (HAS_BIAS) bvv = bias[orow];
#pragma unroll
      for (int n = 0; n < 4; ++n) {
        const int ocol = bcol + wc * 64 + n * 16 + fr;
        st(&C[(size_t)orow * ldc + ocol], acc[m][n][j] * scale + bvv);
      }
    }
  }
}

extern "C" void kernel_launch(void* const* d_in, const int* in_sizes, int n_in,
                              void* d_out, int out_size, void* d_ws, size_t ws_size,
                              hipStream_t stream) {
  const float* tokens = (const float*)d_in[0];
  const float* Wq = (const float*)d_in[1];
  const float* bq = (const float*)d_in[2];
  const float* Wk = (const float*)d_in[3];
  const float* bk = (const float*)d_in[4];
  const float* Wv = (const float*)d_in[5];
  const float* bv = (const float*)d_in[6];
  const float* Wo = (const float*)d_in[7];
  const float* bo = (const float*)d_in[8];
  float* out = (float*)d_out;
  char* ws = (char*)d_ws;
  const size_t MB = 1024ull * 1024ull;
  // workspace layout (peak 180 MB with slot reuse)
  bf16_t* tT = (bf16_t*)(ws + 0);         // tokensT  4 MB   [0,4)
  bf16_t* Wb = (bf16_t*)(ws + 4 * MB);    // weight slot 16 MB [4,20)
  bf16_t* Qm = (bf16_t*)(ws + 20 * MB);   // 32 MB [20,52)
  bf16_t* Km = (bf16_t*)(ws + 52 * MB);   // 32 MB [52,84)
  bf16_t* Vm = (bf16_t*)(ws + 84 * MB);   // 32 MB [84,116)
  bf16_t* Sb = (bf16_t*)(ws + 116 * MB);  // scores/attn 64 MB [116,180)
  bf16_t* Vs = (bf16_t*)(ws + 20 * MB);   // Vsplit 32 MB (reuse Qm after scores)
  bf16_t* cT = (bf16_t*)(ws + 52 * MB);   // ctxT  32 MB (reuse Km after scores)
  float* Pp = (float*)(ws + 116 * MB);    // split-K partials 64 MB (reuse Sb after ctx)

  dim3 b256(256);
  const int nW = HDIM * DMODEL;  // 8388608

  // tokens -> tokensT (bf16)
  transpose_cvt<<<dim3(SEQL / 32, DMODEL / 32), dim3(32, 8), 0, stream>>>(tokens, tT);

  // Q projection: Qm = Wq · tokensT^T + bq
  cvt_f32_bf16<<<nW / 1024, b256, 0, stream>>>(Wq, Wb, nW);
  gemm_bt<bf16_t, true><<<dim3(16, 64, 1), b256, 0, stream>>>(
      Wb, tT, Qm, bq, HDIM, SEQL, DMODEL, DMODEL, DMODEL, SEQL, 0, 0, 0, 1.0f);
  // K projection
  cvt_f32_bf16<<<nW / 1024, b256, 0, stream>>>(Wk, Wb, nW);
  gemm_bt<bf16_t, true><<<dim3(16, 64, 1), b256, 0, stream>>>(
      Wb, tT, Km, bk, HDIM, SEQL, DMODEL, DMODEL, DMODEL, SEQL, 0, 0, 0, 1.0f);
  // V projection
  cvt_f32_bf16<<<nW / 1024, b256, 0, stream>>>(Wv, Wb, nW);
  gemm_bt<bf16_t, true><<<dim3(16, 64, 1), b256, 0, stream>>>(
      Wb, tT, Vm, bv, HDIM, SEQL, DMODEL, DMODEL, DMODEL, SEQL, 0, 0, 0, 1.0f);

  // scores[h][l,m] = (1/32) dot(Qm[l*8192 + h*1024 + :], Km[m*8192 + h*1024 + :])
  gemm_bt<bf16_t, false><<<dim3(16, 16, 8), b256, 0, stream>>>(
      Qm, Km, Sb, nullptr, SEQL, SEQL, DMODEL, HDIM, HDIM, SEQL,
      1024, 1024, (long long)SEQL * SEQL, 0.03125f);

  // softmax over heads (dim 0), in place
  softmax_heads<<<(SEQL * SEQL / 8) / 256, b256, 0, stream>>>(Sb);

  // Vsplit gather
  vsplit_k<<<dim3(SEQL / 32, DMODEL / 32, 8), dim3(32, 8), 0, stream>>>(Vm, Vs);

  // ctxT[l, h*1024+d] = sum_m attn[h][l,m] * Vsplit[h][d,m]
  gemm_bt<bf16_t, false><<<dim3(8, 16, 8), b256, 0, stream>>>(
      Sb, Vs, cT, nullptr, SEQL, DMODEL, SEQL, SEQL, SEQL, HDIM,
      (long long)SEQL * SEQL, (long long)DMODEL * SEQL, DMODEL, 1.0f);

  // out = Wo · ctxT^T + bo  (f32 output), split-K=8 over K=8192
  cvt_f32_bf16<<<nW / 1024, b256, 0, stream>>>(Wo, Wb, nW);
  gemm_bt<float, false><<<dim3(16, 8, 8), b256, 0, stream>>>(
      Wb, cT, Pp, nullptr, DMODEL, SEQL, 1024, HDIM, HDIM, SEQL,
      1024, 1024, (long long)DMODEL * SEQL, 1.0f);
  reduce_out<<<(DMODEL * SEQL / 4) / 256, b256, 0, stream>>>(Pp, bo, out);
}

// Round 3
// 526.469 us; speedup vs baseline: 1.2297x; 1.0472x over previous
//
#include <hip/hip_runtime.h>

#define SEQL 2048
#define DMODEL 1024
#define HDIM 8192  // H*D

typedef unsigned short bf16_t;
typedef __attribute__((ext_vector_type(8))) short bf16x8;
typedef __attribute__((ext_vector_type(4))) float f32x4;

__device__ __forceinline__ bf16_t f2bf(float f) {
  unsigned u = __float_as_uint(f);
  u += 0x7fffu + ((u >> 16) & 1u);  // RNE
  return (bf16_t)(u >> 16);
}
__device__ __forceinline__ float bf2f(bf16_t b) {
  return __uint_as_float(((unsigned)b) << 16);
}
__device__ __forceinline__ void st(bf16_t* p, float v) { *p = f2bf(v); }
__device__ __forceinline__ void st(float* p, float v) { *p = v; }

// ---------------- elementwise f32 -> bf16 ----------------
__global__ __launch_bounds__(256) void cvt_f32_bf16(const float* __restrict__ in,
                                                    bf16_t* __restrict__ out, int n) {
  int i = (blockIdx.x * 256 + threadIdx.x) * 4;
  if (i >= n) return;
  float4 f = *reinterpret_cast<const float4*>(in + i);
  ushort4 u;
  u.x = f2bf(f.x); u.y = f2bf(f.y); u.z = f2bf(f.z); u.w = f2bf(f.w);
  *reinterpret_cast<ushort4*>(out + i) = u;
}

// tokens (DMODEL x SEQL) f32 -> tokensT (SEQL x DMODEL) bf16
__global__ __launch_bounds__(256) void transpose_cvt(const float* __restrict__ in,
                                                     bf16_t* __restrict__ out) {
  __shared__ float tile[32][33];
  int bx = blockIdx.x * 32;  // seq j
  int by = blockIdx.y * 32;  // channel c
  int tx = threadIdx.x, ty = threadIdx.y;
#pragma unroll
  for (int i = ty; i < 32; i += 8)
    tile[i][tx] = in[(size_t)(by + i) * SEQL + bx + tx];
  __syncthreads();
#pragma unroll
  for (int i = ty; i < 32; i += 8)
    out[(size_t)(bx + i) * DMODEL + by + tx] = f2bf(tile[tx][i]);
}

// Vsplit[h][d][m] = Vm[4m+h2, r*1024+d]  (h = 2*h2 + r), bf16 -> bf16
__global__ __launch_bounds__(256) void vsplit_k(const bf16_t* __restrict__ Vm,
                                                bf16_t* __restrict__ Vs) {
  __shared__ bf16_t tile[32][33];
  int h = blockIdx.z, h2 = h >> 1, r = h & 1;
  int m0 = blockIdx.x * 32, d0 = blockIdx.y * 32;
  int tx = threadIdx.x, ty = threadIdx.y;
#pragma unroll
  for (int i = ty; i < 32; i += 8)  // i: m offset, tx: d offset
    tile[i][tx] = Vm[(size_t)(4 * (m0 + i) + h2) * SEQL + r * DMODEL + d0 + tx];
  __syncthreads();
#pragma unroll
  for (int i = ty; i < 32; i += 8)  // i: d offset, tx: m offset
    Vs[((size_t)h * DMODEL + d0 + i) * SEQL + m0 + tx] = tile[tx][i];
}

// softmax over the 8 heads (dim 0), in place on bf16 S[8][L*L]
__global__ __launch_bounds__(256) void softmax_heads(bf16_t* __restrict__ S) {
  const size_t HS = (size_t)SEQL * SEQL;
  size_t p = ((size_t)blockIdx.x * 256 + threadIdx.x) * 8;
  float v[8][8];
#pragma unroll
  for (int h = 0; h < 8; ++h) {
    bf16x8 x = *reinterpret_cast<const bf16x8*>(S + h * HS + p);
#pragma unroll
    for (int e = 0; e < 8; ++e) v[h][e] = bf2f((bf16_t)x[e]);
  }
#pragma unroll
  for (int e = 0; e < 8; ++e) {
    float mx = v[0][e];
#pragma unroll
    for (int h = 1; h < 8; ++h) mx = fmaxf(mx, v[h][e]);
    float s = 0.f;
#pragma unroll
    for (int h = 0; h < 8; ++h) { v[h][e] = __expf(v[h][e] - mx); s += v[h][e]; }
    float inv = 1.0f / s;
#pragma unroll
    for (int h = 0; h < 8; ++h) v[h][e] *= inv;
  }
#pragma unroll
  for (int h = 0; h < 8; ++h) {
    bf16x8 x;
#pragma unroll
    for (int e = 0; e < 8; ++e) x[e] = (short)f2bf(v[h][e]);
    *reinterpret_cast<bf16x8*>(S + h * HS + p) = x;
  }
}

// reduce 8 f32 split-K partials P[z][D][L] -> out[D][L] + bias[row]
__global__ __launch_bounds__(256) void reduce_out(const float* __restrict__ P,
                                                  const float* __restrict__ bo,
                                                  float* __restrict__ out) {
  const size_t NEL = (size_t)DMODEL * SEQL;
  size_t i = ((size_t)blockIdx.x * 256 + threadIdx.x) * 4;
  float4 a = *reinterpret_cast<const float4*>(P + i);
#pragma unroll
  for (int z = 1; z < 8; ++z) {
    float4 b = *reinterpret_cast<const float4*>(P + z * NEL + i);
    a.x += b.x; a.y += b.y; a.z += b.z; a.w += b.w;
  }
  float bias = bo[i / SEQL];
  a.x += bias; a.y += bias; a.z += bias; a.w += bias;
  *reinterpret_cast<float4*>(out + i) = a;
}

// ---------------- C = scale * A·B^T (+bias[row]) ----------------
// A: M x K (row stride lda), B: N x K (row stride ldb), both bf16 K-contiguous.
// 128x128 tile, 4 waves (2x2 of 64x64), BK=32, mfma_f32_16x16x32_bf16.
// Double-buffered prefetch-early K-loop (minimum 2-phase, m230 idiom):
// stage tile t+1 BEFORE computing tile t; single __syncthreads per tile
// (its implicit vmcnt(0)+lgkmcnt(0) is the only drain).
// LDS tiles XOR-swizzled BOTH SIDES (rule #21): chunk slot s of row r holds
// k-chunk s ^ ((r>>1)&3); global source pre-swizzled to match the linear
// global_load_lds destination -> 2-way bank aliasing (free) on ds_read_b128.
// Grid is 1D (gx*gy per z-slice), XCD-chunked bijective swizzle (T1) for L2
// locality; requires gridDim.x % 8 == 0 (all call sites comply) else no-swz.
template <typename OutT, bool HAS_BIAS>
__global__ __launch_bounds__(256) void gemm_bt(
    const bf16_t* __restrict__ A, const bf16_t* __restrict__ B,
    OutT* __restrict__ C, const float* __restrict__ bias,
    int M, int N, int K, int lda, int ldb, int ldc,
    long long sA, long long sB, long long sC, float scale, int gx) {
  __shared__ alignas(16) bf16_t As[2][128 * 32];
  __shared__ alignas(16) bf16_t Bs[2][128 * 32];
  const int z = blockIdx.z;
  A += (long long)z * sA;
  B += (long long)z * sB;
  C += (long long)z * sC;
  const int nwg = gridDim.x;
  const int bid = blockIdx.x;
  const int swz = (nwg & 7) ? bid : ((bid & 7) * (nwg >> 3) + (bid >> 3));
  const int brow = (swz / gx) * 128;
  const int bcol = (swz % gx) * 128;
  const int t = threadIdx.x;
  const int w = t >> 6, lane = t & 63;
  const int fr = lane & 15, fq = lane >> 4;
  const int wr = w >> 1, wc = w & 1;

  // staging offsets: per wave, 2 chunks of A and B each (wave-uniform LDS base
  // ci*1024B + lane*16B; global source pre-swizzled).
  int srow[2], sc8[2];
#pragma unroll
  for (int i = 0; i < 2; ++i) {
    const int idx = (w + i * 4) * 64 + lane;  // 0..511 (16B units)
    const int row = idx >> 2;                 // 0..127
    const int s = idx & 3;                    // physical slot in row
    srow[i] = row;
    sc8[i] = (s ^ ((row >> 1) & 3)) << 3;     // swizzled k-chunk
  }

  auto STAGE = [&](int buf, int kk) {
#pragma unroll
    for (int i = 0; i < 2; ++i) {
      const int ci = w + i * 4;
      const bf16_t* ga = A + (size_t)(brow + srow[i]) * lda + kk + sc8[i];
      const bf16_t* gb = B + (size_t)(bcol + srow[i]) * ldb + kk + sc8[i];
      __builtin_amdgcn_global_load_lds(
          (const __attribute__((address_space(1))) void*)ga,
          (__attribute__((address_space(3))) void*)(&As[buf][ci * 512]), 16, 0, 0);
      __builtin_amdgcn_global_load_lds(
          (const __attribute__((address_space(1))) void*)gb,
          (__attribute__((address_space(3))) void*)(&Bs[buf][ci * 512]), 16, 0, 0);
    }
  };

  f32x4 acc[4][4];
  const f32x4 fzero = {0.f, 0.f, 0.f, 0.f};
#pragma unroll
  for (int m = 0; m < 4; ++m)
#pragma unroll
    for (int n = 0; n < 4; ++n) acc[m][n] = fzero;

  auto COMPUTE = [&](int buf) {
    bf16x8 af[4], bg[4];
#pragma unroll
    for (int m = 0; m < 4; ++m) {
      const int row = wr * 64 + m * 16 + fr;
      af[m] = *reinterpret_cast<const bf16x8*>(
          &As[buf][row * 32 + ((fq ^ ((row >> 1) & 3)) << 3)]);
    }
#pragma unroll
    for (int n = 0; n < 4; ++n) {
      const int row = wc * 64 + n * 16 + fr;
      bg[n] = *reinterpret_cast<const bf16x8*>(
          &Bs[buf][row * 32 + ((fq ^ ((row >> 1) & 3)) << 3)]);
    }
#pragma unroll
    for (int m = 0; m < 4; ++m)
#pragma unroll
      for (int n = 0; n < 4; ++n)
        acc[m][n] = __builtin_amdgcn_mfma_f32_16x16x32_bf16(af[m], bg[n], acc[m][n], 0, 0, 0);
  };

  // K must be a multiple of 64 (all call sites: 1024 or 2048).
  STAGE(0, 0);
  __syncthreads();
  for (int kk = 0; kk < K; kk += 64) {
    STAGE(1, kk + 32);
    COMPUTE(0);
    __syncthreads();
    if (kk + 64 < K) STAGE(0, kk + 64);
    COMPUTE(1);
    __syncthreads();
  }

  // epilogue: C/D layout col = lane&15, row = (lane>>4)*4 + j  (m89/m91)
#pragma unroll
  for (int m = 0; m < 4; ++m) {
#pragma unroll
    for (int j = 0; j < 4; ++j) {
      const int orow = brow + wr * 64 + m * 16 + fq * 4 + j;
      float bvv = 0.f;
      if (HAS_BIAS) bvv = bias[orow];
#pragma unroll
      for (int n = 0; n < 4; ++n) {
        const int ocol = bcol + wc * 64 + n * 16 + fr;
        st(&C[(size_t)orow * ldc + ocol], acc[m][n][j] * scale + bvv);
      }
    }
  }
}

extern "C" void kernel_launch(void* const* d_in, const int* in_sizes, int n_in,
                              void* d_out, int out_size, void* d_ws, size_t ws_size,
                              hipStream_t stream) {
  const float* tokens = (const float*)d_in[0];
  const float* Wq = (const float*)d_in[1];
  const float* bq = (const float*)d_in[2];
  const float* Wk = (const float*)d_in[3];
  const float* bk = (const float*)d_in[4];
  const float* Wv = (const float*)d_in[5];
  const float* bv = (const float*)d_in[6];
  const float* Wo = (const float*)d_in[7];
  const float* bo = (const float*)d_in[8];
  float* out = (float*)d_out;
  char* ws = (char*)d_ws;
  const size_t MB = 1024ull * 1024ull;
  // workspace layout (peak 180 MB with slot reuse)
  bf16_t* tT = (bf16_t*)(ws + 0);         // tokensT  4 MB   [0,4)
  bf16_t* Wb = (bf16_t*)(ws + 4 * MB);    // weight slot 16 MB [4,20)
  bf16_t* Qm = (bf16_t*)(ws + 20 * MB);   // 32 MB [20,52)
  bf16_t* Km = (bf16_t*)(ws + 52 * MB);   // 32 MB [52,84)
  bf16_t* Vm = (bf16_t*)(ws + 84 * MB);   // 32 MB [84,116)
  bf16_t* Sb = (bf16_t*)(ws + 116 * MB);  // scores/attn 64 MB [116,180)
  bf16_t* Vs = (bf16_t*)(ws + 20 * MB);   // Vsplit 32 MB (reuse Qm after scores)
  bf16_t* cT = (bf16_t*)(ws + 52 * MB);   // ctxT  32 MB (reuse Km after scores)
  float* Pp = (float*)(ws + 116 * MB);    // split-K partials 64 MB (reuse Sb after ctx)

  dim3 b256(256);
  const int nW = HDIM * DMODEL;  // 8388608

  // tokens -> tokensT (bf16)
  transpose_cvt<<<dim3(SEQL / 32, DMODEL / 32), dim3(32, 8), 0, stream>>>(tokens, tT);

  // Q projection: Qm = Wq · tokensT^T + bq
  cvt_f32_bf16<<<nW / 1024, b256, 0, stream>>>(Wq, Wb, nW);
  gemm_bt<bf16_t, true><<<dim3(16 * 64, 1, 1), b256, 0, stream>>>(
      Wb, tT, Qm, bq, HDIM, SEQL, DMODEL, DMODEL, DMODEL, SEQL, 0, 0, 0, 1.0f, 16);
  // K projection
  cvt_f32_bf16<<<nW / 1024, b256, 0, stream>>>(Wk, Wb, nW);
  gemm_bt<bf16_t, true><<<dim3(16 * 64, 1, 1), b256, 0, stream>>>(
      Wb, tT, Km, bk, HDIM, SEQL, DMODEL, DMODEL, DMODEL, SEQL, 0, 0, 0, 1.0f, 16);
  // V projection
  cvt_f32_bf16<<<nW / 1024, b256, 0, stream>>>(Wv, Wb, nW);
  gemm_bt<bf16_t, true><<<dim3(16 * 64, 1, 1), b256, 0, stream>>>(
      Wb, tT, Vm, bv, HDIM, SEQL, DMODEL, DMODEL, DMODEL, SEQL, 0, 0, 0, 1.0f, 16);

  // scores[h][l,m] = (1/32) dot(Qm[l*8192 + h*1024 + :], Km[m*8192 + h*1024 + :])
  gemm_bt<bf16_t, false><<<dim3(16 * 16, 1, 8), b256, 0, stream>>>(
      Qm, Km, Sb, nullptr, SEQL, SEQL, DMODEL, HDIM, HDIM, SEQL,
      1024, 1024, (long long)SEQL * SEQL, 0.03125f, 16);

  // softmax over heads (dim 0), in place
  softmax_heads<<<(SEQL * SEQL / 8) / 256, b256, 0, stream>>>(Sb);

  // Vsplit gather
  vsplit_k<<<dim3(SEQL / 32, DMODEL / 32, 8), dim3(32, 8), 0, stream>>>(Vm, Vs);

  // ctxT[l, h*1024+d] = sum_m attn[h][l,m] * Vsplit[h][d,m]
  gemm_bt<bf16_t, false><<<dim3(8 * 16, 1, 8), b256, 0, stream>>>(
      Sb, Vs, cT, nullptr, SEQL, DMODEL, SEQL, SEQL, SEQL, HDIM,
      (long long)SEQL * SEQL, (long long)DMODEL * SEQL, DMODEL, 1.0f, 8);

  // out = Wo · ctxT^T + bo  (f32 output), split-K=8 over K=8192
  cvt_f32_bf16<<<nW / 1024, b256, 0, stream>>>(Wo, Wb, nW);
  gemm_bt<float, false><<<dim3(16 * 8, 1, 8), b256, 0, stream>>>(
      Wb, cT, Pp, nullptr, DMODEL, SEQL, 1024, HDIM, HDIM, SEQL,
      1024, 1024, (long long)DMODEL * SEQL, 1.0f, 16);
  reduce_out<<<(DMODEL * SEQL / 4) / 256, b256, 0, stream>>>(Pp, bo, out);
}

// Round 4
// 501.064 us; speedup vs baseline: 1.2921x; 1.0507x over previous
//
#include <hip/hip_runtime.h>

#define SEQL 2048
#define DMODEL 1024
#define HDIM 8192  // H*D

typedef unsigned short bf16_t;
typedef __attribute__((ext_vector_type(8))) short bf16x8;
typedef __attribute__((ext_vector_type(4))) float f32x4;

__device__ __forceinline__ bf16_t f2bf(float f) {
  unsigned u = __float_as_uint(f);
  u += 0x7fffu + ((u >> 16) & 1u);  // RNE
  return (bf16_t)(u >> 16);
}
__device__ __forceinline__ float bf2f(bf16_t b) {
  return __uint_as_float(((unsigned)b) << 16);
}
__device__ __forceinline__ void st(bf16_t* p, float v) { *p = f2bf(v); }
__device__ __forceinline__ void st(float* p, float v) { *p = v; }

// ---------------- elementwise f32 -> bf16 ----------------
__global__ __launch_bounds__(256) void cvt_f32_bf16(const float* __restrict__ in,
                                                    bf16_t* __restrict__ out, int n) {
  int i = (blockIdx.x * 256 + threadIdx.x) * 4;
  if (i >= n) return;
  float4 f = *reinterpret_cast<const float4*>(in + i);
  ushort4 u;
  u.x = f2bf(f.x); u.y = f2bf(f.y); u.z = f2bf(f.z); u.w = f2bf(f.w);
  *reinterpret_cast<ushort4*>(out + i) = u;
}

// tokens (DMODEL x SEQL) f32 -> tokensT (SEQL x DMODEL) bf16
__global__ __launch_bounds__(256) void transpose_cvt(const float* __restrict__ in,
                                                     bf16_t* __restrict__ out) {
  __shared__ float tile[32][33];
  int bx = blockIdx.x * 32;  // seq j
  int by = blockIdx.y * 32;  // channel c
  int tx = threadIdx.x, ty = threadIdx.y;
#pragma unroll
  for (int i = ty; i < 32; i += 8)
    tile[i][tx] = in[(size_t)(by + i) * SEQL + bx + tx];
  __syncthreads();
#pragma unroll
  for (int i = ty; i < 32; i += 8)
    out[(size_t)(bx + i) * DMODEL + by + tx] = f2bf(tile[tx][i]);
}

// Vsplit[h][d][m] = Vm[4m+h2, r*1024+d]  (h = 2*h2 + r), bf16 -> bf16
__global__ __launch_bounds__(256) void vsplit_k(const bf16_t* __restrict__ Vm,
                                                bf16_t* __restrict__ Vs) {
  __shared__ bf16_t tile[32][33];
  int h = blockIdx.z, h2 = h >> 1, r = h & 1;
  int m0 = blockIdx.x * 32, d0 = blockIdx.y * 32;
  int tx = threadIdx.x, ty = threadIdx.y;
#pragma unroll
  for (int i = ty; i < 32; i += 8)  // i: m offset, tx: d offset
    tile[i][tx] = Vm[(size_t)(4 * (m0 + i) + h2) * SEQL + r * DMODEL + d0 + tx];
  __syncthreads();
#pragma unroll
  for (int i = ty; i < 32; i += 8)  // i: d offset, tx: m offset
    Vs[((size_t)h * DMODEL + d0 + i) * SEQL + m0 + tx] = tile[tx][i];
}

// softmax over the 8 heads (dim 0), in place on bf16 S[8][L*L]
__global__ __launch_bounds__(256) void softmax_heads(bf16_t* __restrict__ S) {
  const size_t HS = (size_t)SEQL * SEQL;
  size_t p = ((size_t)blockIdx.x * 256 + threadIdx.x) * 8;
  float v[8][8];
#pragma unroll
  for (int h = 0; h < 8; ++h) {
    bf16x8 x = *reinterpret_cast<const bf16x8*>(S + h * HS + p);
#pragma unroll
    for (int e = 0; e < 8; ++e) v[h][e] = bf2f((bf16_t)x[e]);
  }
#pragma unroll
  for (int e = 0; e < 8; ++e) {
    float mx = v[0][e];
#pragma unroll
    for (int h = 1; h < 8; ++h) mx = fmaxf(mx, v[h][e]);
    float s = 0.f;
#pragma unroll
    for (int h = 0; h < 8; ++h) { v[h][e] = __expf(v[h][e] - mx); s += v[h][e]; }
    float inv = 1.0f / s;
#pragma unroll
    for (int h = 0; h < 8; ++h) v[h][e] *= inv;
  }
#pragma unroll
  for (int h = 0; h < 8; ++h) {
    bf16x8 x;
#pragma unroll
    for (int e = 0; e < 8; ++e) x[e] = (short)f2bf(v[h][e]);
    *reinterpret_cast<bf16x8*>(S + h * HS + p) = x;
  }
}

// reduce 8 f32 split-K partials P[z][D][L] -> out[D][L] + bias[row]
__global__ __launch_bounds__(256) void reduce_out(const float* __restrict__ P,
                                                  const float* __restrict__ bo,
                                                  float* __restrict__ out) {
  const size_t NEL = (size_t)DMODEL * SEQL;
  size_t i = ((size_t)blockIdx.x * 256 + threadIdx.x) * 4;
  float4 a = *reinterpret_cast<const float4*>(P + i);
#pragma unroll
  for (int z = 1; z < 8; ++z) {
    float4 b = *reinterpret_cast<const float4*>(P + z * NEL + i);
    a.x += b.x; a.y += b.y; a.z += b.z; a.w += b.w;
  }
  float bias = bo[i / SEQL];
  a.x += bias; a.y += bias; a.z += bias; a.w += bias;
  *reinterpret_cast<float4*>(out + i) = a;
}

// ---------------- C = scale * A·B^T (+bias[row]) ----------------
// A: M x K (row stride lda), B: N x K (row stride ldb), both bf16 K-contiguous.
// 128x128 tile, 4 waves (2x2 of 64x64), BK=32, mfma_f32_16x16x32_bf16.
// TRIPLE-buffered K-pipeline with COUNTED vmcnt (T3+T4, m218 idiom):
//   iter t: STAGE(tile t+2); s_waitcnt vmcnt(8) [tiles t+1,t+2 stay in
//   flight -> tile t resident]; s_barrier; ds_read tile t; lgkmcnt(0);
//   s_barrier [write-after-read guard for tile t's buffer]; 16 MFMA.
// Raw s_barrier (no implicit vmcnt(0) drain); loads get ~2 compute iters
// of latency cover. All barriers in block-uniform control flow.
// LDS tiles XOR-swizzled BOTH SIDES (rule #21): chunk slot s of row r holds
// k-chunk s ^ ((r>>1)&3); global source pre-swizzled to match the linear
// global_load_lds destination -> conflict-free ds_read_b128 (measured 0).
// Grid 1D (gx*gy per z-slice), XCD-chunked bijective swizzle (T1).
template <typename OutT, bool HAS_BIAS>
__global__ __launch_bounds__(256) void gemm_bt(
    const bf16_t* __restrict__ A, const bf16_t* __restrict__ B,
    OutT* __restrict__ C, const float* __restrict__ bias,
    int M, int N, int K, int lda, int ldb, int ldc,
    long long sA, long long sB, long long sC, float scale, int gx) {
  __shared__ alignas(16) bf16_t As[3][128 * 32];
  __shared__ alignas(16) bf16_t Bs[3][128 * 32];
  const int z = blockIdx.z;
  A += (long long)z * sA;
  B += (long long)z * sB;
  C += (long long)z * sC;
  const int nwg = gridDim.x;
  const int bid = blockIdx.x;
  const int swz = (nwg & 7) ? bid : ((bid & 7) * (nwg >> 3) + (bid >> 3));
  const int brow = (swz / gx) * 128;
  const int bcol = (swz % gx) * 128;
  const int t0 = threadIdx.x;
  const int w = t0 >> 6, lane = t0 & 63;
  const int fr = lane & 15, fq = lane >> 4;
  const int wr = w >> 1, wc = w & 1;

  // staging offsets: per wave, 2 chunks of A and B each (wave-uniform LDS base
  // ci*1024B + lane*16B; global source pre-swizzled).
  int srow[2], sc8[2];
#pragma unroll
  for (int i = 0; i < 2; ++i) {
    const int idx = (w + i * 4) * 64 + lane;  // 0..511 (16B units)
    const int row = idx >> 2;                 // 0..127
    const int s = idx & 3;                    // physical slot in row
    srow[i] = row;
    sc8[i] = (s ^ ((row >> 1) & 3)) << 3;     // swizzled k-chunk
  }

  auto STAGE = [&](int buf, int kk) {
#pragma unroll
    for (int i = 0; i < 2; ++i) {
      const int ci = w + i * 4;
      const bf16_t* ga = A + (size_t)(brow + srow[i]) * lda + kk + sc8[i];
      const bf16_t* gb = B + (size_t)(bcol + srow[i]) * ldb + kk + sc8[i];
      __builtin_amdgcn_global_load_lds(
          (const __attribute__((address_space(1))) void*)ga,
          (__attribute__((address_space(3))) void*)(&As[buf][ci * 512]), 16, 0, 0);
      __builtin_amdgcn_global_load_lds(
          (const __attribute__((address_space(1))) void*)gb,
          (__attribute__((address_space(3))) void*)(&Bs[buf][ci * 512]), 16, 0, 0);
    }
  };

  f32x4 acc[4][4];
  const f32x4 fzero = {0.f, 0.f, 0.f, 0.f};
#pragma unroll
  for (int m = 0; m < 4; ++m)
#pragma unroll
    for (int n = 0; n < 4; ++n) acc[m][n] = fzero;

  // barrier-1 already passed (vmcnt counted): tile in buf is LDS-resident.
  auto COMPUTE = [&](int buf) {
    bf16x8 af[4], bg[4];
#pragma unroll
    for (int m = 0; m < 4; ++m) {
      const int row = wr * 64 + m * 16 + fr;
      af[m] = *reinterpret_cast<const bf16x8*>(
          &As[buf][row * 32 + ((fq ^ ((row >> 1) & 3)) << 3)]);
    }
#pragma unroll
    for (int n = 0; n < 4; ++n) {
      const int row = wc * 64 + n * 16 + fr;
      bg[n] = *reinterpret_cast<const bf16x8*>(
          &Bs[buf][row * 32 + ((fq ^ ((row >> 1) & 3)) << 3)]);
    }
    // all ds_reads issued; drain them, then barrier-2: after this point every
    // wave's reads of this buffer are complete -> safe to re-STAGE it.
    asm volatile("s_waitcnt lgkmcnt(0)" ::: "memory");
    __builtin_amdgcn_sched_barrier(0);
    __builtin_amdgcn_s_barrier();
    __builtin_amdgcn_s_setprio(1);
#pragma unroll
    for (int m = 0; m < 4; ++m)
#pragma unroll
      for (int n = 0; n < 4; ++n)
        acc[m][n] = __builtin_amdgcn_mfma_f32_16x16x32_bf16(af[m], bg[n], acc[m][n], 0, 0, 0);
    __builtin_amdgcn_s_setprio(0);
  };

  // K multiple of 32, NT >= 3 at all call sites (K = 1024 or 2048).
  const int NT = K >> 5;
  STAGE(0, 0);
  STAGE(1, 32);
  int b = 0;
  for (int t = 0; t < NT - 2; ++t) {
    int sb = b + 2; if (sb >= 3) sb -= 3;
    STAGE(sb, (t + 2) * 32);
    asm volatile("s_waitcnt vmcnt(8)" ::: "memory");  // tiles t+1,t+2 in flight
    __builtin_amdgcn_sched_barrier(0);
    __builtin_amdgcn_s_barrier();
    COMPUTE(b);
    ++b; if (b >= 3) b = 0;
  }
  // tile NT-2: only tile NT-1 (4 loads) may remain in flight
  asm volatile("s_waitcnt vmcnt(4)" ::: "memory");
  __builtin_amdgcn_sched_barrier(0);
  __builtin_amdgcn_s_barrier();
  COMPUTE(b);
  ++b; if (b >= 3) b = 0;
  // tile NT-1: drain everything
  asm volatile("s_waitcnt vmcnt(0)" ::: "memory");
  __builtin_amdgcn_sched_barrier(0);
  __builtin_amdgcn_s_barrier();
  COMPUTE(b);

  // epilogue: C/D layout col = lane&15, row = (lane>>4)*4 + j  (m89/m91)
#pragma unroll
  for (int m = 0; m < 4; ++m) {
#pragma unroll
    for (int j = 0; j < 4; ++j) {
      const int orow = brow + wr * 64 + m * 16 + fq * 4 + j;
      float bvv = 0.f;
      if (HAS_BIAS) bvv = bias[orow];
#pragma unroll
      for (int n = 0; n < 4; ++n) {
        const int ocol = bcol + wc * 64 + n * 16 + fr;
        st(&C[(size_t)orow * ldc + ocol], acc[m][n][j] * scale + bvv);
      }
    }
  }
}

extern "C" void kernel_launch(void* const* d_in, const int* in_sizes, int n_in,
                              void* d_out, int out_size, void* d_ws, size_t ws_size,
                              hipStream_t stream) {
  const float* tokens = (const float*)d_in[0];
  const float* Wq = (const float*)d_in[1];
  const float* bq = (const float*)d_in[2];
  const float* Wk = (const float*)d_in[3];
  const float* bk = (const float*)d_in[4];
  const float* Wv = (const float*)d_in[5];
  const float* bv = (const float*)d_in[6];
  const float* Wo = (const float*)d_in[7];
  const float* bo = (const float*)d_in[8];
  float* out = (float*)d_out;
  char* ws = (char*)d_ws;
  const size_t MB = 1024ull * 1024ull;
  // workspace layout (peak 180 MB with slot reuse)
  bf16_t* tT = (bf16_t*)(ws + 0);         // tokensT  4 MB   [0,4)
  bf16_t* Wb = (bf16_t*)(ws + 4 * MB);    // weight slot 16 MB [4,20)
  bf16_t* Qm = (bf16_t*)(ws + 20 * MB);   // 32 MB [20,52)
  bf16_t* Km = (bf16_t*)(ws + 52 * MB);   // 32 MB [52,84)
  bf16_t* Vm = (bf16_t*)(ws + 84 * MB);   // 32 MB [84,116)
  bf16_t* Sb = (bf16_t*)(ws + 116 * MB);  // scores/attn 64 MB [116,180)
  bf16_t* Vs = (bf16_t*)(ws + 20 * MB);   // Vsplit 32 MB (reuse Qm after scores)
  bf16_t* cT = (bf16_t*)(ws + 52 * MB);   // ctxT  32 MB (reuse Km after scores)
  float* Pp = (float*)(ws + 116 * MB);    // split-K partials 64 MB (reuse Sb after ctx)

  dim3 b256(256);
  const int nW = HDIM * DMODEL;  // 8388608

  // tokens -> tokensT (bf16)
  transpose_cvt<<<dim3(SEQL / 32, DMODEL / 32), dim3(32, 8), 0, stream>>>(tokens, tT);

  // Q projection: Qm = Wq · tokensT^T + bq
  cvt_f32_bf16<<<nW / 1024, b256, 0, stream>>>(Wq, Wb, nW);
  gemm_bt<bf16_t, true><<<dim3(16 * 64, 1, 1), b256, 0, stream>>>(
      Wb, tT, Qm, bq, HDIM, SEQL, DMODEL, DMODEL, DMODEL, SEQL, 0, 0, 0, 1.0f, 16);
  // K projection
  cvt_f32_bf16<<<nW / 1024, b256, 0, stream>>>(Wk, Wb, nW);
  gemm_bt<bf16_t, true><<<dim3(16 * 64, 1, 1), b256, 0, stream>>>(
      Wb, tT, Km, bk, HDIM, SEQL, DMODEL, DMODEL, DMODEL, SEQL, 0, 0, 0, 1.0f, 16);
  // V projection
  cvt_f32_bf16<<<nW / 1024, b256, 0, stream>>>(Wv, Wb, nW);
  gemm_bt<bf16_t, true><<<dim3(16 * 64, 1, 1), b256, 0, stream>>>(
      Wb, tT, Vm, bv, HDIM, SEQL, DMODEL, DMODEL, DMODEL, SEQL, 0, 0, 0, 1.0f, 16);

  // scores[h][l,m] = (1/32) dot(Qm[l*8192 + h*1024 + :], Km[m*8192 + h*1024 + :])
  gemm_bt<bf16_t, false><<<dim3(16 * 16, 1, 8), b256, 0, stream>>>(
      Qm, Km, Sb, nullptr, SEQL, SEQL, DMODEL, HDIM, HDIM, SEQL,
      1024, 1024, (long long)SEQL * SEQL, 0.03125f, 16);

  // softmax over heads (dim 0), in place
  softmax_heads<<<(SEQL * SEQL / 8) / 256, b256, 0, stream>>>(Sb);

  // Vsplit gather
  vsplit_k<<<dim3(SEQL / 32, DMODEL / 32, 8), dim3(32, 8), 0, stream>>>(Vm, Vs);

  // ctxT[l, h*1024+d] = sum_m attn[h][l,m] * Vsplit[h][d,m]
  gemm_bt<bf16_t, false><<<dim3(8 * 16, 1, 8), b256, 0, stream>>>(
      Sb, Vs, cT, nullptr, SEQL, DMODEL, SEQL, SEQL, SEQL, HDIM,
      (long long)SEQL * SEQL, (long long)DMODEL * SEQL, DMODEL, 1.0f, 8);

  // out = Wo · ctxT^T + bo  (f32 output), split-K=8 over K=8192
  cvt_f32_bf16<<<nW / 1024, b256, 0, stream>>>(Wo, Wb, nW);
  gemm_bt<float, false><<<dim3(16 * 8, 1, 8), b256, 0, stream>>>(
      Wb, cT, Pp, nullptr, DMODEL, SEQL, 1024, HDIM, HDIM, SEQL,
      1024, 1024, (long long)DMODEL * SEQL, 1.0f, 16);
  reduce_out<<<(DMODEL * SEQL / 4) / 256, b256, 0, stream>>>(Pp, bo, out);
}

// Round 5
// 422.661 us; speedup vs baseline: 1.5318x; 1.1855x over previous
//
#include <hip/hip_runtime.h>

#define SEQL 2048
#define DMODEL 1024
#define HDIM 8192  // H*D

typedef unsigned short bf16_t;
typedef __attribute__((ext_vector_type(8))) short bf16x8;
typedef __attribute__((ext_vector_type(4))) float f32x4;

__device__ __forceinline__ bf16_t f2bf(float f) {
  unsigned u = __float_as_uint(f);
  u += 0x7fffu + ((u >> 16) & 1u);  // RNE
  return (bf16_t)(u >> 16);
}
__device__ __forceinline__ float bf2f(bf16_t b) {
  return __uint_as_float(((unsigned)b) << 16);
}
__device__ __forceinline__ void st(bf16_t* p, float v) { *p = f2bf(v); }
__device__ __forceinline__ void st(float* p, float v) { *p = v; }

// ---------------- elementwise f32 -> bf16 ----------------
__global__ __launch_bounds__(256) void cvt_f32_bf16(const float* __restrict__ in,
                                                    bf16_t* __restrict__ out, int n) {
  int i = (blockIdx.x * 256 + threadIdx.x) * 4;
  if (i >= n) return;
  float4 f = *reinterpret_cast<const float4*>(in + i);
  ushort4 u;
  u.x = f2bf(f.x); u.y = f2bf(f.y); u.z = f2bf(f.z); u.w = f2bf(f.w);
  *reinterpret_cast<ushort4*>(out + i) = u;
}

// tokens (DMODEL x SEQL) f32 -> tokensT (SEQL x DMODEL) bf16
__global__ __launch_bounds__(256) void transpose_cvt(const float* __restrict__ in,
                                                     bf16_t* __restrict__ out) {
  __shared__ float tile[32][33];
  int bx = blockIdx.x * 32;  // seq j
  int by = blockIdx.y * 32;  // channel c
  int tx = threadIdx.x, ty = threadIdx.y;
#pragma unroll
  for (int i = ty; i < 32; i += 8)
    tile[i][tx] = in[(size_t)(by + i) * SEQL + bx + tx];
  __syncthreads();
#pragma unroll
  for (int i = ty; i < 32; i += 8)
    out[(size_t)(bx + i) * DMODEL + by + tx] = f2bf(tile[tx][i]);
}

// Vsplit[h][d][m] = Vm[4m+h2, r*1024+d]  (h = 2*h2 + r), bf16 -> bf16
__global__ __launch_bounds__(256) void vsplit_k(const bf16_t* __restrict__ Vm,
                                                bf16_t* __restrict__ Vs) {
  __shared__ bf16_t tile[32][33];
  int h = blockIdx.z, h2 = h >> 1, r = h & 1;
  int m0 = blockIdx.x * 32, d0 = blockIdx.y * 32;
  int tx = threadIdx.x, ty = threadIdx.y;
#pragma unroll
  for (int i = ty; i < 32; i += 8)  // i: m offset, tx: d offset
    tile[i][tx] = Vm[(size_t)(4 * (m0 + i) + h2) * SEQL + r * DMODEL + d0 + tx];
  __syncthreads();
#pragma unroll
  for (int i = ty; i < 32; i += 8)  // i: d offset, tx: m offset
    Vs[((size_t)h * DMODEL + d0 + i) * SEQL + m0 + tx] = tile[tx][i];
}

// softmax over the 8 heads (dim 0), in place on bf16 S[8][L*L]
__global__ __launch_bounds__(256) void softmax_heads(bf16_t* __restrict__ S) {
  const size_t HS = (size_t)SEQL * SEQL;
  size_t p = ((size_t)blockIdx.x * 256 + threadIdx.x) * 8;
  float v[8][8];
#pragma unroll
  for (int h = 0; h < 8; ++h) {
    bf16x8 x = *reinterpret_cast<const bf16x8*>(S + h * HS + p);
#pragma unroll
    for (int e = 0; e < 8; ++e) v[h][e] = bf2f((bf16_t)x[e]);
  }
#pragma unroll
  for (int e = 0; e < 8; ++e) {
    float mx = v[0][e];
#pragma unroll
    for (int h = 1; h < 8; ++h) mx = fmaxf(mx, v[h][e]);
    float s = 0.f;
#pragma unroll
    for (int h = 0; h < 8; ++h) { v[h][e] = __expf(v[h][e] - mx); s += v[h][e]; }
    float inv = 1.0f / s;
#pragma unroll
    for (int h = 0; h < 8; ++h) v[h][e] *= inv;
  }
#pragma unroll
  for (int h = 0; h < 8; ++h) {
    bf16x8 x;
#pragma unroll
    for (int e = 0; e < 8; ++e) x[e] = (short)f2bf(v[h][e]);
    *reinterpret_cast<bf16x8*>(S + h * HS + p) = x;
  }
}

// reduce 8 f32 split-K partials P[z][D][L] -> out[D][L] + bias[row]
__global__ __launch_bounds__(256) void reduce_out(const float* __restrict__ P,
                                                  const float* __restrict__ bo,
                                                  float* __restrict__ out) {
  const size_t NEL = (size_t)DMODEL * SEQL;
  size_t i = ((size_t)blockIdx.x * 256 + threadIdx.x) * 4;
  float4 a = *reinterpret_cast<const float4*>(P + i);
#pragma unroll
  for (int z = 1; z < 8; ++z) {
    float4 b = *reinterpret_cast<const float4*>(P + z * NEL + i);
    a.x += b.x; a.y += b.y; a.z += b.z; a.w += b.w;
  }
  float bias = bo[i / SEQL];
  a.x += bias; a.y += bias; a.z += bias; a.w += bias;
  *reinterpret_cast<float4*>(out + i) = a;
}

// ---------------- C = scale * A·B^T (+bias[row]), 256x256 tile ----------------
// A: M x K (row stride lda), B: N x K (row stride ldb), bf16 K-contiguous.
// 512 threads = 8 waves (2M x 4N); per-wave output 128x64 = 8x4 frags of
// 16x16; BK=64 (2 MFMA k-steps); 64 MFMA / wave / K-tile.
// LDS 128 KiB: A and B tiles each 256x64 stored as 2 halves [128][64],
// double-buffered. One __syncthreads per K-tile (intra-tile there are no
// cross-wave hazards: reads hit buf p, stages write buf 1-p). All 4 half-
// tiles of tile t+1 are staged during groups 0-1 of tile t, so the
// boundary's implicit vmcnt(0) waits on ~2-group-old loads (near-free).
// 8-slot XOR swizzle both sides (rule #21): LDS (row r, slot s) holds global
// k-chunk s ^ (r&7); global_load_lds dest stays linear, source pre-swizzled;
// ds_read_b128 per 16-lane group spreads over all 8 slots -> 2-way (free).
// Grid 1D per z-slice, XCD-chunked bijective swizzle (T1), nwg % 8 == 0.
template <typename OutT, bool HAS_BIAS>
__global__ __launch_bounds__(512, 2) void gemm256(
    const bf16_t* __restrict__ A, const bf16_t* __restrict__ B,
    OutT* __restrict__ C, const float* __restrict__ bias,
    int M, int N, int K, int lda, int ldb, int ldc,
    long long sA, long long sB, long long sC, float scale, int gx) {
  __shared__ alignas(16) bf16_t As[2][2][128 * 64];
  __shared__ alignas(16) bf16_t Bs[2][2][128 * 64];
  const int z = blockIdx.z;
  A += (long long)z * sA;
  B += (long long)z * sB;
  C += (long long)z * sC;
  const int nwg = gridDim.x;
  const int bid = blockIdx.x;
  const int swz = (nwg & 7) ? bid : ((bid & 7) * (nwg >> 3) + (bid >> 3));
  const int brow = (swz / gx) * 256;
  const int bcol = (swz % gx) * 256;
  const int tid = threadIdx.x;
  const int w = tid >> 6, lane = tid & 63;
  const int fr = lane & 15, fq = lane >> 4;
  const int wr = w >> 2, wc = w & 3;

  // staging map: half-tile = 128x64 bf16 = 16KB = 8 waves x 2 loads x 64
  // lanes x 16B. Load j of wave w covers LDS bytes (w*2+j)*1024 + lane*16
  // = chunk c = (w*2+j)*64+lane; row rj = c>>3, phys slot c&7 holds global
  // k-chunk (c&7) ^ (rj&7).
  int rj[2], cj[2];
#pragma unroll
  for (int j = 0; j < 2; ++j) {
    const int c = (w * 2 + j) * 64 + lane;
    rj[j] = c >> 3;
    cj[j] = ((c & 7) ^ (rj[j] & 7)) << 3;
  }

  auto stageA = [&](int buf, int half, int kk) {
#pragma unroll
    for (int j = 0; j < 2; ++j) {
      const bf16_t* g = A + (size_t)(brow + half * 128 + rj[j]) * lda + kk + cj[j];
      __builtin_amdgcn_global_load_lds(
          (const __attribute__((address_space(1))) void*)g,
          (__attribute__((address_space(3))) void*)(&As[buf][half][(w * 2 + j) * 512]),
          16, 0, 0);
    }
  };
  auto stageB = [&](int buf, int half, int kk) {
#pragma unroll
    for (int j = 0; j < 2; ++j) {
      const bf16_t* g = B + (size_t)(bcol + half * 128 + rj[j]) * ldb + kk + cj[j];
      __builtin_amdgcn_global_load_lds(
          (const __attribute__((address_space(1))) void*)g,
          (__attribute__((address_space(3))) void*)(&Bs[buf][half][(w * 2 + j) * 512]),
          16, 0, 0);
    }
  };

  // fragment reads (swizzled): logical k-chunk = kk*4+fq at row rr.
  auto ldA = [&](int buf, int mf, int kk) -> bf16x8 {
    const int rr = mf * 16 + fr;
    return *reinterpret_cast<const bf16x8*>(
        &As[buf][wr][rr * 64 + ((((kk << 2) | fq) ^ (rr & 7)) << 3)]);
  };
  auto ldB = [&](int buf, int nf, int kk) -> bf16x8 {
    const int rr = (wc & 1) * 64 + nf * 16 + fr;
    return *reinterpret_cast<const bf16x8*>(
        &Bs[buf][wc >> 1][rr * 64 + ((((kk << 2) | fq) ^ (rr & 7)) << 3)]);
  };

  f32x4 acc[8][4];
  const f32x4 fzero = {0.f, 0.f, 0.f, 0.f};
#pragma unroll
  for (int m = 0; m < 8; ++m)
#pragma unroll
    for (int n = 0; n < 4; ++n) acc[m][n] = fzero;

  const int NT = K >> 6;  // K % 64 == 0, NT >= 2 at all call sites
  stageA(0, 0, 0); stageA(0, 1, 0); stageB(0, 0, 0); stageB(0, 1, 0);
  __syncthreads();

  for (int t = 0; t < NT; ++t) {
    const int p = t & 1, q = p ^ 1;
    const int kn = (t + 1) << 6;
    const bool pre = (t + 1 < NT);
    bf16x8 af[4][2], bg[4][2];

    // ---- group 0: rows 0-63 x cols 0-31 ----
    if (pre) { stageA(q, 0, kn); stageA(q, 1, kn); }
#pragma unroll
    for (int mf = 0; mf < 4; ++mf)
#pragma unroll
      for (int kk = 0; kk < 2; ++kk) af[mf][kk] = ldA(p, mf, kk);
#pragma unroll
    for (int nf = 0; nf < 2; ++nf)
#pragma unroll
      for (int kk = 0; kk < 2; ++kk) bg[nf][kk] = ldB(p, nf, kk);
    __builtin_amdgcn_s_setprio(1);
#pragma unroll
    for (int mf = 0; mf < 4; ++mf)
#pragma unroll
      for (int nf = 0; nf < 2; ++nf)
#pragma unroll
        for (int kk = 0; kk < 2; ++kk)
          acc[mf][nf] = __builtin_amdgcn_mfma_f32_16x16x32_bf16(
              af[mf][kk], bg[nf][kk], acc[mf][nf], 0, 0, 0);
    __builtin_amdgcn_s_setprio(0);

    // ---- group 1: rows 0-63 x cols 32-63 ----
    if (pre) { stageB(q, 0, kn); stageB(q, 1, kn); }
#pragma unroll
    for (int nf = 2; nf < 4; ++nf)
#pragma unroll
      for (int kk = 0; kk < 2; ++kk) bg[nf][kk] = ldB(p, nf, kk);
    __builtin_amdgcn_s_setprio(1);
#pragma unroll
    for (int mf = 0; mf < 4; ++mf)
#pragma unroll
      for (int nf = 2; nf < 4; ++nf)
#pragma unroll
        for (int kk = 0; kk < 2; ++kk)
          acc[mf][nf] = __builtin_amdgcn_mfma_f32_16x16x32_bf16(
              af[mf][kk], bg[nf][kk], acc[mf][nf], 0, 0, 0);
    __builtin_amdgcn_s_setprio(0);

    // ---- group 2: rows 64-127 x cols 32-63 ----
#pragma unroll
    for (int mf = 0; mf < 4; ++mf)
#pragma unroll
      for (int kk = 0; kk < 2; ++kk) af[mf][kk] = ldA(p, mf + 4, kk);
    __builtin_amdgcn_s_setprio(1);
#pragma unroll
    for (int mf = 0; mf < 4; ++mf)
#pragma unroll
      for (int nf = 2; nf < 4; ++nf)
#pragma unroll
        for (int kk = 0; kk < 2; ++kk)
          acc[mf + 4][nf] = __builtin_amdgcn_mfma_f32_16x16x32_bf16(
              af[mf][kk], bg[nf][kk], acc[mf + 4][nf], 0, 0, 0);
    __builtin_amdgcn_s_setprio(0);

    // ---- group 3: rows 64-127 x cols 0-31 ----
#pragma unroll
    for (int nf = 0; nf < 2; ++nf)
#pragma unroll
      for (int kk = 0; kk < 2; ++kk) bg[nf][kk] = ldB(p, nf, kk);
    __builtin_amdgcn_s_setprio(1);
#pragma unroll
    for (int mf = 0; mf < 4; ++mf)
#pragma unroll
      for (int nf = 0; nf < 2; ++nf)
#pragma unroll
        for (int kk = 0; kk < 2; ++kk)
          acc[mf + 4][nf] = __builtin_amdgcn_mfma_f32_16x16x32_bf16(
              af[mf][kk], bg[nf][kk], acc[mf + 4][nf], 0, 0, 0);
    __builtin_amdgcn_s_setprio(0);

    // boundary: implicit vmcnt(0)+lgkmcnt(0)+barrier. RAW: tile t+1 staged
    // loads landed. WAR: every wave's ds_reads of buf p retired (consumed by
    // MFMAs above) -> next iter may overwrite buf p... (it stages buf q'=p).
    if (pre) __syncthreads();
  }

  // epilogue: C/D layout col = lane&15, row = (lane>>4)*4 + j  (m89/m91)
#pragma unroll
  for (int mf = 0; mf < 8; ++mf) {
#pragma unroll
    for (int j = 0; j < 4; ++j) {
      const int orow = brow + wr * 128 + mf * 16 + fq * 4 + j;
      float bvv = 0.f;
      if (HAS_BIAS) bvv = bias[orow];
#pragma unroll
      for (int nf = 0; nf < 4; ++nf) {
        const int ocol = bcol + wc * 64 + nf * 16 + fr;
        st(&C[(size_t)orow * ldc + ocol], acc[mf][nf][j] * scale + bvv);
      }
    }
  }
}

extern "C" void kernel_launch(void* const* d_in, const int* in_sizes, int n_in,
                              void* d_out, int out_size, void* d_ws, size_t ws_size,
                              hipStream_t stream) {
  const float* tokens = (const float*)d_in[0];
  const float* Wq = (const float*)d_in[1];
  const float* bq = (const float*)d_in[2];
  const float* Wk = (const float*)d_in[3];
  const float* bk = (const float*)d_in[4];
  const float* Wv = (const float*)d_in[5];
  const float* bv = (const float*)d_in[6];
  const float* Wo = (const float*)d_in[7];
  const float* bo = (const float*)d_in[8];
  float* out = (float*)d_out;
  char* ws = (char*)d_ws;
  const size_t MB = 1024ull * 1024ull;
  // workspace layout (peak 180 MB with slot reuse)
  bf16_t* tT = (bf16_t*)(ws + 0);         // tokensT  4 MB   [0,4)
  bf16_t* Wb = (bf16_t*)(ws + 4 * MB);    // weight slot 16 MB [4,20)
  bf16_t* Qm = (bf16_t*)(ws + 20 * MB);   // 32 MB [20,52)
  bf16_t* Km = (bf16_t*)(ws + 52 * MB);   // 32 MB [52,84)
  bf16_t* Vm = (bf16_t*)(ws + 84 * MB);   // 32 MB [84,116)
  bf16_t* Sb = (bf16_t*)(ws + 116 * MB);  // scores/attn 64 MB [116,180)
  bf16_t* Vs = (bf16_t*)(ws + 20 * MB);   // Vsplit 32 MB (reuse Qm after scores)
  bf16_t* cT = (bf16_t*)(ws + 52 * MB);   // ctxT  32 MB (reuse Km after scores)
  float* Pp = (float*)(ws + 116 * MB);    // split-K partials 64 MB (reuse Sb after ctx)

  dim3 b256(256);
  dim3 b512(512);
  const int nW = HDIM * DMODEL;  // 8388608

  // tokens -> tokensT (bf16)
  transpose_cvt<<<dim3(SEQL / 32, DMODEL / 32), dim3(32, 8), 0, stream>>>(tokens, tT);

  // Q projection: Qm = Wq · tokensT^T + bq   (M=8192,N=2048,K=1024)
  cvt_f32_bf16<<<nW / 1024, b256, 0, stream>>>(Wq, Wb, nW);
  gemm256<bf16_t, true><<<dim3(32 * 8, 1, 1), b512, 0, stream>>>(
      Wb, tT, Qm, bq, HDIM, SEQL, DMODEL, DMODEL, DMODEL, SEQL, 0, 0, 0, 1.0f, 8);
  // K projection
  cvt_f32_bf16<<<nW / 1024, b256, 0, stream>>>(Wk, Wb, nW);
  gemm256<bf16_t, true><<<dim3(32 * 8, 1, 1), b512, 0, stream>>>(
      Wb, tT, Km, bk, HDIM, SEQL, DMODEL, DMODEL, DMODEL, SEQL, 0, 0, 0, 1.0f, 8);
  // V projection
  cvt_f32_bf16<<<nW / 1024, b256, 0, stream>>>(Wv, Wb, nW);
  gemm256<bf16_t, true><<<dim3(32 * 8, 1, 1), b512, 0, stream>>>(
      Wb, tT, Vm, bv, HDIM, SEQL, DMODEL, DMODEL, DMODEL, SEQL, 0, 0, 0, 1.0f, 8);

  // scores[h][l,m] = (1/32) dot(Qm[l*8192 + h*1024 + :], Km[m*8192 + h*1024 + :])
  gemm256<bf16_t, false><<<dim3(8 * 8, 1, 8), b512, 0, stream>>>(
      Qm, Km, Sb, nullptr, SEQL, SEQL, DMODEL, HDIM, HDIM, SEQL,
      1024, 1024, (long long)SEQL * SEQL, 0.03125f, 8);

  // softmax over heads (dim 0), in place
  softmax_heads<<<(SEQL * SEQL / 8) / 256, b256, 0, stream>>>(Sb);

  // Vsplit gather
  vsplit_k<<<dim3(SEQL / 32, DMODEL / 32, 8), dim3(32, 8), 0, stream>>>(Vm, Vs);

  // ctxT[l, h*1024+d] = sum_m attn[h][l,m] * Vsplit[h][d,m]  (M=2048,N=1024,K=2048)
  gemm256<bf16_t, false><<<dim3(8 * 4, 1, 8), b512, 0, stream>>>(
      Sb, Vs, cT, nullptr, SEQL, DMODEL, SEQL, SEQL, SEQL, HDIM,
      (long long)SEQL * SEQL, (long long)DMODEL * SEQL, DMODEL, 1.0f, 4);

  // out = Wo · ctxT^T + bo  (f32 output), split-K=8 over K=8192
  cvt_f32_bf16<<<nW / 1024, b256, 0, stream>>>(Wo, Wb, nW);
  gemm256<float, false><<<dim3(4 * 8, 1, 8), b512, 0, stream>>>(
      Wb, cT, Pp, nullptr, DMODEL, SEQL, 1024, HDIM, HDIM, SEQL,
      1024, 1024, (long long)DMODEL * SEQL, 1.0f, 8);
  reduce_out<<<(DMODEL * SEQL / 4) / 256, b256, 0, stream>>>(Pp, bo, out);
}